// Round 3
// baseline (138.477 us; speedup 1.0000x reference)
//
#include <hip/hip_runtime.h>
#include <cmath>

#define BB 8
#define CC 128
#define NN 16384
#define HH 4
#define TN 64                    // n positions per sub-tile
#define TPB 4                    // sub-tiles per block in pass1
#define NT_TOTAL (NN / TN)       // 256
#define P1_GROUPS (NT_TOTAL / TPB) // 64
#define SLOTS (P1_GROUPS * 2)    // kv partial slots per batch

typedef __attribute__((ext_vector_type(8))) short bf16x8;
typedef __attribute__((ext_vector_type(4))) float f32x4;

#define MFMA(a, b, c) __builtin_amdgcn_mfma_f32_16x16x32_bf16(a, b, c, 0, 0, 0)

// fp32 -> bf16 (RNE)
__device__ __forceinline__ unsigned short f2b(float f) {
  union { float f; unsigned u; } v; v.f = f;
  unsigned r = v.u + 0x7FFFu + ((v.u >> 16) & 1u);
  return (unsigned short)(r >> 16);
}

// xT / XT layout: [n][c] bf16, 256 B per n-row, XOR-swizzle on 16B blocks
__device__ __forceinline__ int xt_byte(int n, int c) {
  return n * 256 + ((((c >> 3) ^ (n & 15)) << 4) | ((c & 7) << 1));
}
// KT/VT layout: [c][n] bf16, 144 B/row stride, XOR-swizzle on 16B blocks
__device__ __forceinline__ int kt_byte(int c, int n) {
  return c * 144 + ((((n >> 3) ^ (c & 7)) << 4) | ((n & 7) << 1));
}

// ---------------------------------------------------------------------------
// K0: convert Wq,Wk,Wv,Wo fp32[128][128] -> bf16 (same layout)
// ---------------------------------------------------------------------------
__global__ void k_prep(const float* __restrict__ Wq, const float* __restrict__ Wk,
                       const float* __restrict__ Wv, const float* __restrict__ Wo,
                       unsigned short* __restrict__ Wb) {
  const int idx = blockIdx.x * 256 + threadIdx.x;   // < 65536
  const int which = idx >> 14;
  const float* src = (which == 0) ? Wq : (which == 1) ? Wk : (which == 2) ? Wv : Wo;
  Wb[idx] = f2b(src[idx & 16383]);
}

// ---------------------------------------------------------------------------
// K1: x fp32 [b][c][n] -> xT bf16 [b][n][c], pre-swizzled (xt_byte layout).
// Reads: 1 KB contiguous per channel row per instruction (streaming).
// Writes: 64 KB fully contiguous per block.
// ---------------------------------------------------------------------------
__global__ __launch_bounds__(512, 4)
void k_xpose(const float* __restrict__ x, unsigned char* __restrict__ xT) {
  extern __shared__ char lds[];   // 64 KB: [256 n][256 B]
  const int tid = threadIdx.x;
  const int lane = tid & 63;
  const int w = tid >> 6;
  const int b = blockIdx.y;
  const int n0 = blockIdx.x * 256;

#pragma unroll
  for (int r = 0; r < 16; ++r) {
    const int c = w * 16 + r;
    const float4 v4 = *(const float4*)(x + ((size_t)b * CC + c) * NN + n0 + lane * 4);
    const float vv[4] = {v4.x, v4.y, v4.z, v4.w};
#pragma unroll
    for (int j = 0; j < 4; ++j) {
      const int n = lane * 4 + j;
      *(unsigned short*)(lds + xt_byte(n, c)) = f2b(vv[j]);
    }
  }
  __syncthreads();
  unsigned char* dst = xT + ((size_t)b * NN + n0) * 256;
#pragma unroll
  for (int i = 0; i < 8; ++i) {
    const int off = i * 8192 + tid * 16;
    *(float4*)(dst + off) = *(const float4*)(lds + off);
  }
}

// ---------------------------------------------------------------------------
// K2: K,V projection + per-head LN + partial K^T V   (MFMA)
// waves: proj phase (head = w>>1, proj = w&1); kv phase (head = w>>1, half = w&1)
// ---------------------------------------------------------------------------
__global__ __launch_bounds__(512, 4)
void k_pass1(const unsigned char* __restrict__ xT,
             const unsigned short* __restrict__ Wkb, const unsigned short* __restrict__ Wvb,
             const float* __restrict__ bk, const float* __restrict__ bv,
             const float* __restrict__ gK, const float* __restrict__ bK,
             const float* __restrict__ gV, const float* __restrict__ bV,
             float* __restrict__ kvp) {
  extern __shared__ char lds[];
  char* XT = lds;               // 16384 B
  char* KT = lds + 16384;       // 18432 B
  char* VT = lds + 34816;       // 18432 B

  const int tid = threadIdx.x;
  const int lane = tid & 63;
  const int w = tid >> 6;
  const int b = blockIdx.y;
  const int l15 = lane & 15, l4 = lane >> 4;

  const int ph = w >> 1;        // head (proj phase)
  const int pp = w & 1;         // 0=K, 1=V
  const int kh = w >> 1, khalf = w & 1;   // kv phase roles

  // W fragments in registers: A-operand, row = l15 (c_out), k = ks*32 + l4*8 + j
  const unsigned short* Wsrc = pp ? Wvb : Wkb;
  bf16x8 wf[2][4];
#pragma unroll
  for (int mf = 0; mf < 2; ++mf)
#pragma unroll
    for (int ks = 0; ks < 4; ++ks)
      wf[mf][ks] = *(const bf16x8*)(Wsrc + (ph * 32 + mf * 16 + l15) * 128 + ks * 32 + l4 * 8);

  // bias / gamma / beta for this lane's channels: c_local = mf*16 + l4*4 + r
  float bias[2][4], gam[2][4], bet[2][4];
  {
    const float* bsrc = pp ? bv : bk;
    const float* gsrc = pp ? gV : gK;
    const float* esrc = pp ? bV : bK;
#pragma unroll
    for (int mf = 0; mf < 2; ++mf)
#pragma unroll
      for (int r = 0; r < 4; ++r) {
        const int cg = ph * 32 + mf * 16 + l4 * 4 + r;
        bias[mf][r] = bsrc[cg]; gam[mf][r] = gsrc[cg]; bet[mf][r] = esrc[cg];
      }
  }

  f32x4 kvacc[2][2];
#pragma unroll
  for (int i = 0; i < 2; ++i)
#pragma unroll
    for (int j = 0; j < 2; ++j) kvacc[i][j] = (f32x4){0.f, 0.f, 0.f, 0.f};

  for (int t = 0; t < TPB; ++t) {
    const int n0 = (blockIdx.x * TPB + t) * TN;

    // Phase A: linear coalesced copy of pre-swizzled xT sub-tile (16 KB)
    {
      const unsigned char* src = xT + ((size_t)b * NN + n0) * 256;
#pragma unroll
      for (int i = 0; i < 2; ++i) {
        const int off = i * 8192 + tid * 16;
        *(float4*)(XT + off) = *(const float4*)(src + off);
      }
    }
    __syncthreads();

    // Phase B: projection GEMM, D[c][n] = W * X
    f32x4 acc[2][4];
#pragma unroll
    for (int mf = 0; mf < 2; ++mf)
#pragma unroll
      for (int nf = 0; nf < 4; ++nf) acc[mf][nf] = (f32x4){0.f, 0.f, 0.f, 0.f};
#pragma unroll
    for (int ks = 0; ks < 4; ++ks)
#pragma unroll
      for (int nf = 0; nf < 4; ++nf) {
        const int n = nf * 16 + l15;
        const bf16x8 xf = *(const bf16x8*)(XT + n * 256 + (((ks * 4 + l4) ^ (n & 15)) << 4));
        acc[0][nf] = MFMA(wf[0][ks], xf, acc[0][nf]);
        acc[1][nf] = MFMA(wf[1][ks], xf, acc[1][nf]);
      }
    // bias
#pragma unroll
    for (int mf = 0; mf < 2; ++mf)
#pragma unroll
      for (int nf = 0; nf < 4; ++nf)
#pragma unroll
        for (int r = 0; r < 4; ++r) acc[mf][nf][r] += bias[mf][r];
    // per-head LayerNorm (32 channels, per position n) + stage bf16 to KT/VT
    char* DST = pp ? VT : KT;
#pragma unroll
    for (int nf = 0; nf < 4; ++nf) {
      float s = 0.f, ss = 0.f;
#pragma unroll
      for (int mf = 0; mf < 2; ++mf)
#pragma unroll
        for (int r = 0; r < 4; ++r) { const float v = acc[mf][nf][r]; s += v; ss += v * v; }
      s += __shfl_xor(s, 16); ss += __shfl_xor(ss, 16);
      s += __shfl_xor(s, 32); ss += __shfl_xor(ss, 32);
      const float mu = s * (1.f / 32.f);
      const float var = ss * (1.f / 32.f) - mu * mu;
      const float rstd = rsqrtf(var + 1e-5f);
      const int n = nf * 16 + l15;
#pragma unroll
      for (int mf = 0; mf < 2; ++mf)
#pragma unroll
        for (int r = 0; r < 4; ++r) {
          const float a = rstd * gam[mf][r];
          const float vv = (acc[mf][nf][r] - mu) * a + bet[mf][r];
          const int c = ph * 32 + mf * 16 + l4 * 4 + r;
          *(unsigned short*)(DST + kt_byte(c, n)) = f2b(vv);
        }
    }
    __syncthreads();

    // Phase C: kv partial += K^T V over this wave's 32-n half
#pragma unroll
    for (int mf = 0; mf < 2; ++mf) {
      const int ck = kh * 32 + mf * 16 + l15;
      const bf16x8 ka = *(const bf16x8*)(KT + ck * 144 + (((khalf * 4 + l4) ^ (ck & 7)) << 4));
#pragma unroll
      for (int ef = 0; ef < 2; ++ef) {
        const int cv = kh * 32 + ef * 16 + l15;
        const bf16x8 vb = *(const bf16x8*)(VT + cv * 144 + (((khalf * 4 + l4) ^ (cv & 7)) << 4));
        kvacc[mf][ef] = MFMA(ka, vb, kvacc[mf][ef]);
      }
    }
    __syncthreads();   // KT/VT consumed; next iter overwrites XT/KT/VT
  }

  // write kv partials: [b][slot][h][d*32+e] fp32
  const int slot = blockIdx.x * 2 + khalf;
  float* o = kvp + (((size_t)b * SLOTS + slot) * HH + kh) * 1024;
#pragma unroll
  for (int mf = 0; mf < 2; ++mf)
#pragma unroll
    for (int ef = 0; ef < 2; ++ef)
#pragma unroll
      for (int r = 0; r < 4; ++r) {
        const int d = mf * 16 + l4 * 4 + r, e = ef * 16 + l15;
        o[d * 32 + e] = kvacc[mf][ef][r];
      }
}

// ---------------------------------------------------------------------------
// K3: kv reduce over 128 slots (fixed order), scale, store transposed bf16
//     kvT[b][h][e][d]
// ---------------------------------------------------------------------------
__global__ void k_reduce(const float* __restrict__ kvp, unsigned short* __restrict__ kvT,
                         const float scale) {
  __shared__ float red[4][64];
  const int tid = threadIdx.x;
  const int part = tid >> 6;           // wave id 0..3
  const int sl = tid & 63;
  const int ot = blockIdx.x * 64 + sl; // output element: b*4096 + h*1024 + d*32 + e
  const int b = ot >> 12, rem = ot & 4095;
  const float* p = kvp + (size_t)b * SLOTS * (HH * 1024) + rem;
  float s = 0.f;
#pragma unroll 8
  for (int t2 = 0; t2 < SLOTS / 4; ++t2) s += p[(size_t)(part * (SLOTS / 4) + t2) * 4096];
  red[part][sl] = s;
  __syncthreads();
  if (tid < 64) {
    const float tot = (red[0][tid] + red[1][tid] + red[2][tid] + red[3][tid]) * scale;
    const int o2 = blockIdx.x * 64 + tid;
    const int b2 = o2 >> 12, r2 = o2 & 4095;
    const int h = r2 >> 10, d = (r2 >> 5) & 31, e = r2 & 31;
    kvT[(((size_t)b2 * HH + h) * 32 + e) * 32 + d] = f2b(tot);
  }
}

// ---------------------------------------------------------------------------
// K4: Q proj + attn (q @ kv) + output GEMM + bias, coalesced fp32 store
// ---------------------------------------------------------------------------
__global__ __launch_bounds__(512, 4)
void k_pass2(const unsigned char* __restrict__ xT,
             const unsigned short* __restrict__ Wqb, const float* __restrict__ bq,
             const unsigned short* __restrict__ kvT,
             const unsigned short* __restrict__ Wob, const float* __restrict__ bo,
             float* __restrict__ out) {
  extern __shared__ char lds[];
  char* XT = lds;            // 16384
  char* QS = lds + 16384;    // 16384  q as [n][c]
  char* AS = lds + 32768;    // 16384  attn out as [n][c']

  const int tid = threadIdx.x;
  const int lane = tid & 63;
  const int w = tid >> 6;
  const int b = blockIdx.y;
  const int n0 = blockIdx.x * TN;
  const int l15 = lane & 15, l4 = lane >> 4;
  const int h = w >> 1, half = w & 1;

  // kv A-fragments (row = e, k = d) from global bf16 kvT[b][h][e][d]
  bf16x8 kvf[2];
#pragma unroll
  for (int mf = 0; mf < 2; ++mf)
    kvf[mf] = *(const bf16x8*)(kvT + (((size_t)b * HH + h) * 32 + mf * 16 + l15) * 32 + l4 * 8);
  // Wq / Wo fragments for this wave's 16-channel slice
  bf16x8 wq[4], wo[4];
#pragma unroll
  for (int ks = 0; ks < 4; ++ks) {
    wq[ks] = *(const bf16x8*)(Wqb + (w * 16 + l15) * 128 + ks * 32 + l4 * 8);
    wo[ks] = *(const bf16x8*)(Wob + (w * 16 + l15) * 128 + ks * 32 + l4 * 8);
  }
  float bq_r[4], bo_r[4];
#pragma unroll
  for (int r = 0; r < 4; ++r) {
    bq_r[r] = bq[w * 16 + l4 * 4 + r];
    bo_r[r] = bo[w * 16 + l4 * 4 + r];
  }

  // Phase A: linear coalesced copy of pre-swizzled xT sub-tile (16 KB)
  {
    const unsigned char* src = xT + ((size_t)b * NN + n0) * 256;
#pragma unroll
    for (int i = 0; i < 2; ++i) {
      const int off = i * 8192 + tid * 16;
      *(float4*)(XT + off) = *(const float4*)(src + off);
    }
  }
  __syncthreads();

  // Phase B: q-GEMM, D[c][n], c-slice = w*16
  f32x4 qa[4];
#pragma unroll
  for (int nf = 0; nf < 4; ++nf) qa[nf] = (f32x4){0.f, 0.f, 0.f, 0.f};
#pragma unroll
  for (int ks = 0; ks < 4; ++ks)
#pragma unroll
    for (int nf = 0; nf < 4; ++nf) {
      const int n = nf * 16 + l15;
      const bf16x8 xf = *(const bf16x8*)(XT + n * 256 + (((ks * 4 + l4) ^ (n & 15)) << 4));
      qa[nf] = MFMA(wq[ks], xf, qa[nf]);
    }
  // bias + stage q to QS[n][c] (pack 4 consecutive c rows -> b64)
#pragma unroll
  for (int nf = 0; nf < 4; ++nf) {
    const int n = nf * 16 + l15;
    const int c0 = w * 16 + l4 * 4;
    unsigned long long pk = 0;
#pragma unroll
    for (int r = 0; r < 4; ++r)
      pk |= (unsigned long long)f2b(qa[nf][r] + bq_r[r]) << (16 * r);
    *(unsigned long long*)(QS + n * 256 + (((c0 >> 3) ^ (n & 15)) << 4) + ((c0 & 7) << 1)) = pk;
  }
  __syncthreads();

  // Phase C: attn D[e][n] = kv^T(as A) * q(as B), per (head, n-half)
  f32x4 aa[2][2];
#pragma unroll
  for (int i = 0; i < 2; ++i)
#pragma unroll
    for (int j = 0; j < 2; ++j) aa[i][j] = (f32x4){0.f, 0.f, 0.f, 0.f};
  bf16x8 qf[2];
#pragma unroll
  for (int nf = 0; nf < 2; ++nf) {
    const int n = half * 32 + nf * 16 + l15;
    const int cq = h * 32 + l4 * 8;   // d-chunk
    qf[nf] = *(const bf16x8*)(QS + n * 256 + ((((cq >> 3)) ^ (n & 15)) << 4));
  }
#pragma unroll
  for (int mf = 0; mf < 2; ++mf)
#pragma unroll
    for (int nf = 0; nf < 2; ++nf) aa[mf][nf] = MFMA(kvf[mf], qf[nf], aa[mf][nf]);
  // stage attn out to AS[n][c'] (pack 4 consecutive e rows)
#pragma unroll
  for (int mf = 0; mf < 2; ++mf)
#pragma unroll
    for (int nf = 0; nf < 2; ++nf) {
      const int n = half * 32 + nf * 16 + l15;
      const int e0 = h * 32 + mf * 16 + l4 * 4;
      unsigned long long pk = 0;
#pragma unroll
      for (int r = 0; r < 4; ++r)
        pk |= (unsigned long long)f2b(aa[mf][nf][r]) << (16 * r);
      *(unsigned long long*)(AS + n * 256 + (((e0 >> 3) ^ (n & 15)) << 4) + ((e0 & 7) << 1)) = pk;
    }
  __syncthreads();

  // Phase D: out-GEMM, D[c_out][n], c_out-slice = w*16
  f32x4 oa[4];
#pragma unroll
  for (int nf = 0; nf < 4; ++nf) oa[nf] = (f32x4){0.f, 0.f, 0.f, 0.f};
#pragma unroll
  for (int ks = 0; ks < 4; ++ks)
#pragma unroll
    for (int nf = 0; nf < 4; ++nf) {
      const int n = nf * 16 + l15;
      const bf16x8 af = *(const bf16x8*)(AS + n * 256 + (((ks * 4 + l4) ^ (n & 15)) << 4));
      oa[nf] = MFMA(wo[ks], af, oa[nf]);
    }
  float* ob = out + (size_t)b * CC * NN;
#pragma unroll
  for (int nf = 0; nf < 4; ++nf)
#pragma unroll
    for (int r = 0; r < 4; ++r) {
      const int c = w * 16 + l4 * 4 + r;
      ob[(size_t)c * NN + n0 + nf * 16 + l15] = oa[nf][r] + bo_r[r];
    }
}

// ---------------------------------------------------------------------------
extern "C" void kernel_launch(void* const* d_in, const int* in_sizes, int n_in,
                              void* d_out, int out_size, void* d_ws, size_t ws_size,
                              hipStream_t stream) {
  const float* x  = (const float*)d_in[0];
  const float* Wq = (const float*)d_in[1];
  const float* bq = (const float*)d_in[2];
  const float* Wk = (const float*)d_in[3];
  const float* bk = (const float*)d_in[4];
  const float* Wv = (const float*)d_in[5];
  const float* bv = (const float*)d_in[6];
  const float* gK = (const float*)d_in[7];
  const float* bK = (const float*)d_in[8];
  const float* gV = (const float*)d_in[9];
  const float* bV = (const float*)d_in[10];
  const float* Wo = (const float*)d_in[11];
  const float* bo = (const float*)d_in[12];
  float* out = (float*)d_out;

  char* ws = (char*)d_ws;
  float* kvp = (float*)ws;                                   // 8*128*4096 f32 = 16 MB
  unsigned short* kvTb = (unsigned short*)(ws + (size_t)BB * SLOTS * HH * 1024 * 4); // 64 KB
  unsigned short* Wb = kvTb + (size_t)BB * HH * 1024;        // 128 KB
  unsigned char* xT = (unsigned char*)(Wb + 65536);          // 32 MB bf16 [b][n][c] swizzled
  const unsigned short* Wqb = Wb;
  const unsigned short* Wkb = Wb + 16384;
  const unsigned short* Wvb = Wb + 32768;
  const unsigned short* Wob = Wb + 49152;

  (void)hipFuncSetAttribute(reinterpret_cast<const void*>(k_xpose),
                            hipFuncAttributeMaxDynamicSharedMemorySize, 65536);
  (void)hipFuncSetAttribute(reinterpret_cast<const void*>(k_pass1),
                            hipFuncAttributeMaxDynamicSharedMemorySize, 53248);
  (void)hipFuncSetAttribute(reinterpret_cast<const void*>(k_pass2),
                            hipFuncAttributeMaxDynamicSharedMemorySize, 49152);

  k_prep<<<256, 256, 0, stream>>>(Wq, Wk, Wv, Wo, Wb);

  k_xpose<<<dim3(NN / 256, BB), 512, 65536, stream>>>(x, xT);

  k_pass1<<<dim3(P1_GROUPS, BB), 512, 53248, stream>>>(
      xT, Wkb, Wvb, bk, bv, gK, bK, gV, bV, kvp);

  const float scale = 1.0f / (5.65685424949238f * 16384.0f);  // 1/(sqrt(32)*N)
  k_reduce<<<(BB * 4096) / 64, 256, 0, stream>>>(kvp, kvTb, scale);

  k_pass2<<<dim3(NT_TOTAL, BB), 512, 49152, stream>>>(
      xT, Wqb, bq, kvTb, Wob, bo, out);
}

// Round 4
// 93.692 us; speedup vs baseline: 1.4780x; 1.4780x over previous
//
#include <hip/hip_runtime.h>
#include <cmath>

#define BB 8
#define CC 128
#define NN 16384
#define HH 4
#define BN 256                   // fused-kernel n-tile
#define NB (NN / BN)             // 64 blocks per batch (fused)
#define TN 64                    // pass2 n-tile
#define NT2 (NN / TN)            // 256

typedef __attribute__((ext_vector_type(8))) short bf16x8;
typedef __attribute__((ext_vector_type(4))) float f32x4;

#define MFMA(a, b, c) __builtin_amdgcn_mfma_f32_16x16x32_bf16(a, b, c, 0, 0, 0)

// fp32 -> bf16 (RNE)
__device__ __forceinline__ unsigned short f2b(float f) {
  union { float f; unsigned u; } v; v.f = f;
  unsigned r = v.u + 0x7FFFu + ((v.u >> 16) & 1u);
  return (unsigned short)(r >> 16);
}

// xT / XT layout: [n][c] bf16, 256 B per n-row, XOR-swizzle on 16B blocks
__device__ __forceinline__ int xt_byte(int n, int c) {
  return n * 256 + ((((c >> 3) ^ (n & 15)) << 4) | ((c & 7) << 1));
}
// KT/VT layout: [c][n] bf16, 144 B/row stride, XOR-swizzle on 16B blocks
__device__ __forceinline__ int kt_byte(int c, int n) {
  return c * 144 + ((((n >> 3) ^ (c & 7)) << 4) | ((n & 7) << 1));
}

// ---------------------------------------------------------------------------
// K0: convert Wq,Wk,Wv,Wo fp32[128][128] -> bf16 (same layout)
// ---------------------------------------------------------------------------
__global__ void k_prep(const float* __restrict__ Wq, const float* __restrict__ Wk,
                       const float* __restrict__ Wv, const float* __restrict__ Wo,
                       unsigned short* __restrict__ Wb) {
  const int idx = blockIdx.x * 256 + threadIdx.x;   // < 65536
  const int which = idx >> 14;
  const float* src = (which == 0) ? Wq : (which == 1) ? Wk : (which == 2) ? Wv : Wo;
  Wb[idx] = f2b(src[idx & 16383]);
}

// ---------------------------------------------------------------------------
// K1 (fused): per (b, 256-n tile):
//   stage x -> LDS XT (bf16, [n][c] swizzled)  [1 KB-granule streaming reads]
//   dump XT -> global xT (linear, for pass2)
//   4x 64-n sub-tiles: K/V proj (MFMA) + per-head LN + partial K^T V
//   stage kv partials in LDS, dump 32 KB linear to kvp
// LDS: XT 64 KB | KT 18 KB | VT 18 KB  (KT/VT reused as KVS 32 KB at end)
// ---------------------------------------------------------------------------
__global__ __launch_bounds__(512, 2)
void k_fuse1(const float* __restrict__ x, unsigned char* __restrict__ xT,
             const unsigned short* __restrict__ Wkb, const unsigned short* __restrict__ Wvb,
             const float* __restrict__ bk, const float* __restrict__ bv,
             const float* __restrict__ gK, const float* __restrict__ bK,
             const float* __restrict__ gV, const float* __restrict__ bV,
             float* __restrict__ kvp) {
  extern __shared__ char lds[];
  char* XT = lds;                      // 65536 B: [256 n][256 B]
  char* KT = lds + 65536;              // 18432 B
  char* VT = lds + 83968;              // 18432 B
  float* KVS = (float*)(lds + 65536);  // 32 KB, reused after t-loop

  const int tid = threadIdx.x;
  const int lane = tid & 63;
  const int w = tid >> 6;
  const int b = blockIdx.y;
  const int bx = blockIdx.x;
  const int n0 = bx * BN;
  const int l15 = lane & 15, l4 = lane >> 4;

  const int ph = w >> 1;        // head (proj phase)
  const int pp = w & 1;         // 0=K, 1=V
  const int kh = w >> 1, khalf = w & 1;   // kv phase roles

  // W fragments in registers: A-operand, row = l15 (c_out), k = ks*32 + l4*8 + j
  const unsigned short* Wsrc = pp ? Wvb : Wkb;
  bf16x8 wf[2][4];
#pragma unroll
  for (int mf = 0; mf < 2; ++mf)
#pragma unroll
    for (int ks = 0; ks < 4; ++ks)
      wf[mf][ks] = *(const bf16x8*)(Wsrc + (ph * 32 + mf * 16 + l15) * 128 + ks * 32 + l4 * 8);

  float bias[2][4], gam[2][4], bet[2][4];
  {
    const float* bsrc = pp ? bv : bk;
    const float* gsrc = pp ? gV : gK;
    const float* esrc = pp ? bV : bK;
#pragma unroll
    for (int mf = 0; mf < 2; ++mf)
#pragma unroll
      for (int r = 0; r < 4; ++r) {
        const int cg = ph * 32 + mf * 16 + l4 * 4 + r;
        bias[mf][r] = bsrc[cg]; gam[mf][r] = gsrc[cg]; bet[mf][r] = esrc[cg];
      }
  }

  // Phase 1: x (fp32, 1 KB contiguous per channel row) -> XT (bf16 swizzled)
#pragma unroll
  for (int r2 = 0; r2 < 8; ++r2) {
    const int c = w * 16 + r2 * 2;
    const float* xr = x + ((size_t)b * CC + c) * NN + n0 + lane * 4;
    const float4 a0 = *(const float4*)xr;
    const float4 a1 = *(const float4*)(xr + NN);
    const float va0[4] = {a0.x, a0.y, a0.z, a0.w};
    const float va1[4] = {a1.x, a1.y, a1.z, a1.w};
#pragma unroll
    for (int j = 0; j < 4; ++j) {
      const int n = lane * 4 + j;
      const unsigned pk = (unsigned)f2b(va0[j]) | ((unsigned)f2b(va1[j]) << 16);
      *(unsigned*)(XT + xt_byte(n, c)) = pk;
    }
  }
  __syncthreads();

  // Phase 2: dump XT -> global xT (64 KB fully linear; fire-and-forget)
  {
    unsigned char* dst = xT + ((size_t)b * NN + n0) * 256;
#pragma unroll
    for (int i = 0; i < 8; ++i) {
      const int off = i * 8192 + tid * 16;
      *(float4*)(dst + off) = *(const float4*)(XT + off);
    }
  }

  f32x4 kvacc[2][2];
#pragma unroll
  for (int i = 0; i < 2; ++i)
#pragma unroll
    for (int j = 0; j < 2; ++j) kvacc[i][j] = (f32x4){0.f, 0.f, 0.f, 0.f};

  // Phase 3: 4 sub-tiles of 64 n
  for (int t = 0; t < 4; ++t) {
    // proj GEMM: D[c][n] = W * X   (reads XT, stable all iterations)
    f32x4 acc[2][4];
#pragma unroll
    for (int mf = 0; mf < 2; ++mf)
#pragma unroll
      for (int nf = 0; nf < 4; ++nf) acc[mf][nf] = (f32x4){0.f, 0.f, 0.f, 0.f};
#pragma unroll
    for (int ks = 0; ks < 4; ++ks)
#pragma unroll
      for (int nf = 0; nf < 4; ++nf) {
        const int n = t * 64 + nf * 16 + l15;
        const bf16x8 xf = *(const bf16x8*)(XT + n * 256 + (((ks * 4 + l4) ^ (n & 15)) << 4));
        acc[0][nf] = MFMA(wf[0][ks], xf, acc[0][nf]);
        acc[1][nf] = MFMA(wf[1][ks], xf, acc[1][nf]);
      }
#pragma unroll
    for (int mf = 0; mf < 2; ++mf)
#pragma unroll
      for (int nf = 0; nf < 4; ++nf)
#pragma unroll
        for (int r = 0; r < 4; ++r) acc[mf][nf][r] += bias[mf][r];

    // per-head LayerNorm (32 ch per position) + stage bf16 to KT/VT
    char* DST = pp ? VT : KT;
#pragma unroll
    for (int nf = 0; nf < 4; ++nf) {
      float s = 0.f, ss = 0.f;
#pragma unroll
      for (int mf = 0; mf < 2; ++mf)
#pragma unroll
        for (int r = 0; r < 4; ++r) { const float v = acc[mf][nf][r]; s += v; ss += v * v; }
      s += __shfl_xor(s, 16); ss += __shfl_xor(ss, 16);
      s += __shfl_xor(s, 32); ss += __shfl_xor(ss, 32);
      const float mu = s * (1.f / 32.f);
      const float var = ss * (1.f / 32.f) - mu * mu;
      const float rstd = rsqrtf(var + 1e-5f);
      const int n = nf * 16 + l15;
#pragma unroll
      for (int mf = 0; mf < 2; ++mf)
#pragma unroll
        for (int r = 0; r < 4; ++r) {
          const float a = rstd * gam[mf][r];
          const float vv = (acc[mf][nf][r] - mu) * a + bet[mf][r];
          const int c = ph * 32 + mf * 16 + l4 * 4 + r;
          *(unsigned short*)(DST + kt_byte(c, n)) = f2b(vv);
        }
    }
    __syncthreads();

    // kv partial += K^T V over this wave's 32-n half
#pragma unroll
    for (int mf = 0; mf < 2; ++mf) {
      const int ck = kh * 32 + mf * 16 + l15;
      const bf16x8 ka = *(const bf16x8*)(KT + ck * 144 + (((khalf * 4 + l4) ^ (ck & 7)) << 4));
#pragma unroll
      for (int ef = 0; ef < 2; ++ef) {
        const int cv = kh * 32 + ef * 16 + l15;
        const bf16x8 vb = *(const bf16x8*)(VT + cv * 144 + (((khalf * 4 + l4) ^ (cv & 7)) << 4));
        kvacc[mf][ef] = MFMA(ka, vb, kvacc[mf][ef]);
      }
    }
    __syncthreads();   // KT/VT consumed before next iter overwrites
  }

  // Phase 4: stage kv partials -> KVS[w][1024], then 32 KB linear dump
#pragma unroll
  for (int mf = 0; mf < 2; ++mf)
#pragma unroll
    for (int ef = 0; ef < 2; ++ef)
#pragma unroll
      for (int r = 0; r < 4; ++r) {
        const int d = mf * 16 + l4 * 4 + r, e = ef * 16 + l15;
        KVS[w * 1024 + d * 32 + e] = kvacc[mf][ef][r];
      }
  __syncthreads();
  {
    float* o = kvp + ((size_t)(b * NB + bx)) * 8192;
#pragma unroll
    for (int i = 0; i < 4; ++i) {
      const int off = i * 2048 + tid * 4;
      *(f32x4*)(o + off) = *(const f32x4*)(KVS + off);
    }
  }
}

// ---------------------------------------------------------------------------
// K2a: partial reduce of kvp over bx (8 per block) and hf.
//   kvp layout: [b][bx][w=2h+hf][1024]; p2 layout: [b][h][s][1024]
// ---------------------------------------------------------------------------
__global__ void k_reduceA(const float* __restrict__ kvp, float* __restrict__ p2) {
  const int blk = blockIdx.x;           // (b*4+h)*8 + s, 256 blocks
  const int s = blk & 7, h = (blk >> 3) & 3, b = blk >> 5;
  const int t = threadIdx.x;            // 256 threads, float4 each
  f32x4 acc = (f32x4){0.f, 0.f, 0.f, 0.f};
  for (int i = 0; i < 8; ++i) {
    const int bx = s * 8 + i;
    const float* base = kvp + ((size_t)(b * NB + bx)) * 8192 + t * 4;
    acc += *(const f32x4*)(base + (2 * h) * 1024);
    acc += *(const f32x4*)(base + (2 * h + 1) * 1024);
  }
  *(f32x4*)(p2 + (size_t)blk * 1024 + t * 4) = acc;
}

// ---------------------------------------------------------------------------
// K2b: final reduce over s, scale, store kvT[b][h][e][d] bf16
// ---------------------------------------------------------------------------
__global__ void k_reduceB(const float* __restrict__ p2, unsigned short* __restrict__ kvT,
                          const float scale) {
  const int bh = blockIdx.x;            // b*4+h, 32 blocks
  const int t = threadIdx.x;            // 256 threads
  f32x4 acc = (f32x4){0.f, 0.f, 0.f, 0.f};
  for (int s = 0; s < 8; ++s)
    acc += *(const f32x4*)(p2 + ((size_t)bh * 8 + s) * 1024 + t * 4);
#pragma unroll
  for (int j = 0; j < 4; ++j) {
    const int i = t * 4 + j;
    const int d = i >> 5, e = i & 31;
    kvT[(size_t)bh * 1024 + e * 32 + d] = f2b(acc[j] * scale);
  }
}

// ---------------------------------------------------------------------------
// K3: Q proj + attn (q @ kv) + output GEMM + bias; LDS-staged coalesced store
// LDS: XT 16K | QS 16K | AS 16K ; OS (32K fp32) overlays XT+QS in phase D
// ---------------------------------------------------------------------------
__global__ __launch_bounds__(512, 4)
void k_pass2(const unsigned char* __restrict__ xT,
             const unsigned short* __restrict__ Wqb, const float* __restrict__ bq,
             const unsigned short* __restrict__ kvT,
             const unsigned short* __restrict__ Wob, const float* __restrict__ bo,
             float* __restrict__ out) {
  extern __shared__ char lds[];
  char* XT = lds;            // 16384
  char* QS = lds + 16384;    // 16384  q as [n][c]
  char* AS = lds + 32768;    // 16384  attn out as [n][c']
  float* OS = (float*)lds;   // 32768  out staging [c][64], overlays XT+QS

  const int tid = threadIdx.x;
  const int lane = tid & 63;
  const int w = tid >> 6;
  const int b = blockIdx.y;
  const int n0 = blockIdx.x * TN;
  const int l15 = lane & 15, l4 = lane >> 4;
  const int h = w >> 1, half = w & 1;

  // kv A-fragments (row = e, k = d) from global bf16 kvT[b][h][e][d]
  bf16x8 kvf[2];
#pragma unroll
  for (int mf = 0; mf < 2; ++mf)
    kvf[mf] = *(const bf16x8*)(kvT + (((size_t)b * HH + h) * 32 + mf * 16 + l15) * 32 + l4 * 8);
  bf16x8 wq[4], wo[4];
#pragma unroll
  for (int ks = 0; ks < 4; ++ks) {
    wq[ks] = *(const bf16x8*)(Wqb + (w * 16 + l15) * 128 + ks * 32 + l4 * 8);
    wo[ks] = *(const bf16x8*)(Wob + (w * 16 + l15) * 128 + ks * 32 + l4 * 8);
  }
  float bq_r[4], bo_r[4];
#pragma unroll
  for (int r = 0; r < 4; ++r) {
    bq_r[r] = bq[w * 16 + l4 * 4 + r];
    bo_r[r] = bo[w * 16 + l4 * 4 + r];
  }

  // Phase A: linear coalesced copy of pre-swizzled xT sub-tile (16 KB)
  {
    const unsigned char* src = xT + ((size_t)b * NN + n0) * 256;
#pragma unroll
    for (int i = 0; i < 2; ++i) {
      const int off = i * 8192 + tid * 16;
      *(float4*)(XT + off) = *(const float4*)(src + off);
    }
  }
  __syncthreads();

  // Phase B: q-GEMM, D[c][n], c-slice = w*16
  f32x4 qa[4];
#pragma unroll
  for (int nf = 0; nf < 4; ++nf) qa[nf] = (f32x4){0.f, 0.f, 0.f, 0.f};
#pragma unroll
  for (int ks = 0; ks < 4; ++ks)
#pragma unroll
    for (int nf = 0; nf < 4; ++nf) {
      const int n = nf * 16 + l15;
      const bf16x8 xf = *(const bf16x8*)(XT + n * 256 + (((ks * 4 + l4) ^ (n & 15)) << 4));
      qa[nf] = MFMA(wq[ks], xf, qa[nf]);
    }
#pragma unroll
  for (int nf = 0; nf < 4; ++nf) {
    const int n = nf * 16 + l15;
    const int c0 = w * 16 + l4 * 4;
    unsigned long long pk = 0;
#pragma unroll
    for (int r = 0; r < 4; ++r)
      pk |= (unsigned long long)f2b(qa[nf][r] + bq_r[r]) << (16 * r);
    *(unsigned long long*)(QS + n * 256 + (((c0 >> 3) ^ (n & 15)) << 4) + ((c0 & 7) << 1)) = pk;
  }
  __syncthreads();

  // Phase C: attn D[e][n] = kv(as A) * q(as B), per (head, n-half)
  f32x4 aa[2][2];
#pragma unroll
  for (int i = 0; i < 2; ++i)
#pragma unroll
    for (int j = 0; j < 2; ++j) aa[i][j] = (f32x4){0.f, 0.f, 0.f, 0.f};
  bf16x8 qf[2];
#pragma unroll
  for (int nf = 0; nf < 2; ++nf) {
    const int n = half * 32 + nf * 16 + l15;
    const int cq = h * 32 + l4 * 8;
    qf[nf] = *(const bf16x8*)(QS + n * 256 + ((((cq >> 3)) ^ (n & 15)) << 4));
  }
#pragma unroll
  for (int mf = 0; mf < 2; ++mf)
#pragma unroll
    for (int nf = 0; nf < 2; ++nf) aa[mf][nf] = MFMA(kvf[mf], qf[nf], aa[mf][nf]);
#pragma unroll
  for (int mf = 0; mf < 2; ++mf)
#pragma unroll
    for (int nf = 0; nf < 2; ++nf) {
      const int n = half * 32 + nf * 16 + l15;
      const int e0 = h * 32 + mf * 16 + l4 * 4;
      unsigned long long pk = 0;
#pragma unroll
      for (int r = 0; r < 4; ++r)
        pk |= (unsigned long long)f2b(aa[mf][nf][r]) << (16 * r);
      *(unsigned long long*)(AS + n * 256 + (((e0 >> 3) ^ (n & 15)) << 4) + ((e0 & 7) << 1)) = pk;
    }
  __syncthreads();

  // Phase D: out-GEMM, D[c_out][n] -> OS staging (XT/QS dead; AS still read)
  f32x4 oa[4];
#pragma unroll
  for (int nf = 0; nf < 4; ++nf) oa[nf] = (f32x4){0.f, 0.f, 0.f, 0.f};
#pragma unroll
  for (int ks = 0; ks < 4; ++ks)
#pragma unroll
    for (int nf = 0; nf < 4; ++nf) {
      const int n = nf * 16 + l15;
      const bf16x8 af = *(const bf16x8*)(AS + n * 256 + (((ks * 4 + l4) ^ (n & 15)) << 4));
      oa[nf] = MFMA(wo[ks], af, oa[nf]);
    }
#pragma unroll
  for (int nf = 0; nf < 4; ++nf)
#pragma unroll
    for (int r = 0; r < 4; ++r)
      OS[(w * 16 + l4 * 4 + r) * 64 + nf * 16 + l15] = oa[nf][r] + bo_r[r];
  __syncthreads();

  // coalesced dump: thread -> (c = tid>>2, 16-col segment)
  {
    const int c = tid >> 2, seg = (tid & 3) * 16;
    const float* srcp = OS + c * 64 + seg;
    float* dstp = out + (size_t)b * CC * NN + (size_t)c * NN + n0 + seg;
#pragma unroll
    for (int j = 0; j < 4; ++j)
      ((float4*)dstp)[j] = ((const float4*)srcp)[j];
  }
}

// ---------------------------------------------------------------------------
extern "C" void kernel_launch(void* const* d_in, const int* in_sizes, int n_in,
                              void* d_out, int out_size, void* d_ws, size_t ws_size,
                              hipStream_t stream) {
  const float* x  = (const float*)d_in[0];
  const float* Wq = (const float*)d_in[1];
  const float* bq = (const float*)d_in[2];
  const float* Wk = (const float*)d_in[3];
  const float* bk = (const float*)d_in[4];
  const float* Wv = (const float*)d_in[5];
  const float* bv = (const float*)d_in[6];
  const float* gK = (const float*)d_in[7];
  const float* bK = (const float*)d_in[8];
  const float* gV = (const float*)d_in[9];
  const float* bV = (const float*)d_in[10];
  const float* Wo = (const float*)d_in[11];
  const float* bo = (const float*)d_in[12];
  float* out = (float*)d_out;

  char* ws = (char*)d_ws;
  float* kvp = (float*)ws;                                   // 8*64*8192 f32 = 16 MB
  float* p2  = kvp + (size_t)BB * NB * 8192;                 // 256*1024 f32 = 1 MB
  unsigned short* kvTb = (unsigned short*)(p2 + 256 * 1024); // 64 KB
  unsigned short* Wb = kvTb + (size_t)BB * HH * 1024;        // 128 KB
  unsigned char* xT = (unsigned char*)(Wb + 65536);          // 32 MB bf16 [b][n][c] swizzled
  const unsigned short* Wqb = Wb;
  const unsigned short* Wkb = Wb + 16384;
  const unsigned short* Wvb = Wb + 32768;
  const unsigned short* Wob = Wb + 49152;

  (void)hipFuncSetAttribute(reinterpret_cast<const void*>(k_fuse1),
                            hipFuncAttributeMaxDynamicSharedMemorySize, 102400);
  (void)hipFuncSetAttribute(reinterpret_cast<const void*>(k_pass2),
                            hipFuncAttributeMaxDynamicSharedMemorySize, 49152);

  k_prep<<<256, 256, 0, stream>>>(Wq, Wk, Wv, Wo, Wb);

  k_fuse1<<<dim3(NB, BB), 512, 102400, stream>>>(
      x, xT, Wkb, Wvb, bk, bv, gK, bK, gV, bV, kvp);

  k_reduceA<<<256, 256, 0, stream>>>(kvp, p2);

  const float scale = 1.0f / (5.65685424949238f * 16384.0f);  // 1/(sqrt(32)*N)
  k_reduceB<<<32, 256, 0, stream>>>(p2, kvTb, scale);

  k_pass2<<<dim3(NT2, BB), 512, 49152, stream>>>(
      xT, Wqb, bq, kvTb, Wob, bo, out);
}